// Round 3
// baseline (338.697 us; speedup 1.0000x reference)
//
#include <hip/hip_runtime.h>
#include <hip/hip_bf16.h>

#define D_MODEL 1024
#define D_FF    4096
#define SEQ_LEN 2048
#define NBATCH  4
#define NROWS   (NBATCH*SEQ_LEN)   // 8192
#define NCHUNK  32
#define CHUNK_L (SEQ_LEN/NCHUNK)   // 64
#define LN_EPS  1e-5f

typedef __hip_bfloat16 bf16;
typedef __attribute__((ext_vector_type(8))) short bf16x8;
typedef __attribute__((ext_vector_type(4))) float f32x4;

// ---------------- cast f32 -> bf16, vectorized ----------------
__global__ void cast4(const float4* __restrict__ in, ushort4* __restrict__ out, int n4) {
    int i = blockIdx.x * blockDim.x + threadIdx.x;
    if (i < n4) {
        float4 v = in[i];
        union { ushort4 u; bf16 b[4]; } cv;
        cv.b[0] = __float2bfloat16(v.x); cv.b[1] = __float2bfloat16(v.y);
        cv.b[2] = __float2bfloat16(v.z); cv.b[3] = __float2bfloat16(v.w);
        out[i] = cv.u;
    }
}

// ---------------- p, p^64 from phazor ----------------
// p = exp(-|pz|^2) * exp(i*angle(pz)) = exp(-r2) * (re,im)/sqrt(r2)
__global__ void compute_pvec(const float* __restrict__ phz, float* __restrict__ pv) {
    int d = blockIdx.x * blockDim.x + threadIdx.x;
    if (d >= D_MODEL) return;
    float re = phz[2*d], im = phz[2*d+1];
    float r2 = re*re + im*im;
    float mag = expf(-r2);
    float pr, pim;
    if (r2 > 0.f) { float inv = mag / sqrtf(r2); pr = re*inv; pim = im*inv; }
    else          { pr = mag; pim = 0.f; }
    // p^64 by 6 squarings
    float ar = pr, ai = pim;
    #pragma unroll
    for (int i = 0; i < 6; i++) { float nr = ar*ar - ai*ai; float ni = 2.f*ar*ai; ar = nr; ai = ni; }
    pv[d]            = pr;
    pv[D_MODEL+d]    = pim;
    pv[2*D_MODEL+d]  = ar;
    pv[3*D_MODEL+d]  = ai;
}

// ---------------- LayerNorm row kernel (optional f32 and bf16 outputs) ----------------
__global__ __launch_bounds__(256) void ln_fused(const float* __restrict__ x,
                                                const float* __restrict__ g,
                                                const float* __restrict__ bta,
                                                float* __restrict__ outf,
                                                bf16*  __restrict__ outb)
{
    int row = blockIdx.x;
    int tid = threadIdx.x;
    const float4* xr = (const float4*)(x + (size_t)row * D_MODEL);
    float4 v = xr[tid];
    float s  = v.x + v.y + v.z + v.w;
    float s2 = v.x*v.x + v.y*v.y + v.z*v.z + v.w*v.w;
    for (int off = 32; off; off >>= 1) { s += __shfl_down(s, off); s2 += __shfl_down(s2, off); }
    __shared__ float red[8];
    int wid = tid >> 6, lane = tid & 63;
    if (lane == 0) { red[wid] = s; red[4+wid] = s2; }
    __syncthreads();
    if (tid == 0) {
        red[0] = red[0]+red[1]+red[2]+red[3];
        red[4] = red[4]+red[5]+red[6]+red[7];
    }
    __syncthreads();
    float mu  = red[0] * (1.f/D_MODEL);
    float var = red[4] * (1.f/D_MODEL) - mu*mu;
    float rstd = rsqrtf(var + LN_EPS);
    float4 gv = ((const float4*)g)[tid];
    float4 bv = ((const float4*)bta)[tid];
    float4 o;
    o.x = (v.x-mu)*rstd*gv.x + bv.x;
    o.y = (v.y-mu)*rstd*gv.y + bv.y;
    o.z = (v.z-mu)*rstd*gv.z + bv.z;
    o.w = (v.w-mu)*rstd*gv.w + bv.w;
    if (outf) ((float4*)(outf + (size_t)row * D_MODEL))[tid] = o;
    if (outb) {
        union { ushort4 u; bf16 b[4]; } cv;
        cv.b[0]=__float2bfloat16(o.x); cv.b[1]=__float2bfloat16(o.y);
        cv.b[2]=__float2bfloat16(o.z); cv.b[3]=__float2bfloat16(o.w);
        ((ushort4*)(outb + (size_t)row * D_MODEL))[tid] = cv.u;
    }
}

// ---------------- scan pass 1: per-chunk local state (zero init) ----------------
__global__ __launch_bounds__(256) void scan_pass1(const float* __restrict__ xn,
                                                  const float* __restrict__ pv,
                                                  const float* __restrict__ pini,
                                                  float* __restrict__ Sc)
{
    int d = blockIdx.x * 256 + threadIdx.x;
    int c = blockIdx.y, b = blockIdx.z;
    float pr = pv[d], pim = pv[D_MODEL+d];
    float icr = pini[2*d], ici = pini[2*d+1];
    float Sr = 0.f, Si = 0.f;
    const float* xp = xn + ((size_t)b*SEQ_LEN + c*CHUNK_L) * D_MODEL + d;
    #pragma unroll 8
    for (int i = 0; i < CHUNK_L; i++) {
        float xv = xp[(size_t)i * D_MODEL];
        float nr = pr*Sr - pim*Si + icr*xv;
        float ni = pr*Si + pim*Sr + ici*xv;
        Sr = nr; Si = ni;
    }
    size_t o = ((size_t)b*NCHUNK + c) * D_MODEL + d;
    Sc[2*o] = Sr; Sc[2*o+1] = Si;
}

// ---------------- scan pass 2: exclusive prefix over chunks (init = hidden) ----------------
__global__ __launch_bounds__(256) void scan_prefix(const float* __restrict__ Sc,
                                                   const float* __restrict__ pv,
                                                   const float* __restrict__ hr,
                                                   const float* __restrict__ hi,
                                                   float* __restrict__ pref)
{
    int d = blockIdx.x * 256 + threadIdx.x;
    int b = blockIdx.y;
    float qr = pv[2*D_MODEL+d], qi = pv[3*D_MODEL+d];   // p^64
    float Ur = hr[b*D_MODEL+d], Ui = hi[b*D_MODEL+d];
    for (int c = 0; c < NCHUNK; c++) {
        size_t o = ((size_t)b*NCHUNK + c) * D_MODEL + d;
        pref[2*o] = Ur; pref[2*o+1] = Ui;
        float sr = Sc[2*o], si = Sc[2*o+1];
        float nr = qr*Ur - qi*Ui + sr;
        float ni = qr*Ui + qi*Ur + si;
        Ur = nr; Ui = ni;
    }
}

// ---------------- scan pass 3: final states, write conv_with_past ----------------
__global__ __launch_bounds__(256) void scan_pass2(const float* __restrict__ xn,
                                                  const float* __restrict__ pv,
                                                  const float* __restrict__ pini,
                                                  const float* __restrict__ pref,
                                                  float* __restrict__ cwp,
                                                  int interleaved)
{
    int d = blockIdx.x * 256 + threadIdx.x;
    int c = blockIdx.y, b = blockIdx.z;
    float pr = pv[d], pim = pv[D_MODEL+d];
    float icr = pini[2*d], ici = pini[2*d+1];
    size_t po = ((size_t)b*NCHUNK + c) * D_MODEL + d;
    float Ur = pref[2*po], Ui = pref[2*po+1];
    size_t base = ((size_t)b*SEQ_LEN + c*CHUNK_L) * D_MODEL + d;
    const float* xp = xn + base;
    if (interleaved) {
        float2* cp = (float2*)cwp + base;
        #pragma unroll 8
        for (int i = 0; i < CHUNK_L; i++) {
            float xv = xp[(size_t)i * D_MODEL];
            float nr = pr*Ur - pim*Ui + icr*xv;
            float ni = pr*Ui + pim*Ur + ici*xv;
            Ur = nr; Ui = ni;
            cp[(size_t)i * D_MODEL] = make_float2(Ur, Ui);
        }
    } else {
        float* cp = cwp + base;
        #pragma unroll 8
        for (int i = 0; i < CHUNK_L; i++) {
            float xv = xp[(size_t)i * D_MODEL];
            float nr = pr*Ur - pim*Ui + icr*xv;
            float ni = pr*Ui + pim*Ur + ici*xv;
            Ur = nr; Ui = ni;
            cp[(size_t)i * D_MODEL] = Ur;
        }
    }
}

// ---------------- bf16 MFMA GEMM: C[M,N] = A[M,K] @ Bt[N,K]^T, fused epilogues ----------------
// EPI 0: x2 = cwp_real * silu(acc + bias) + x_res   (writes f32)
// EPI 1: h  = silu(acc + bias)                      (writes bf16)
// EPI 2: out = acc + bias + x2                      (writes f32)
#define BM 128
#define BN 128
#define BK 32
#define LDSK 40   // padded leading dim: bank-conflict-free b128 reads

template<int EPI>
__global__ __launch_bounds__(256) void gemm_bt(const bf16* __restrict__ A,
                                               const bf16* __restrict__ Bt,
                                               const float* __restrict__ bias,
                                               const float* __restrict__ e0, int e0_stride,
                                               const float* __restrict__ e1,
                                               float* __restrict__ outf,
                                               bf16*  __restrict__ outb,
                                               int M, int N, int K)
{
    __shared__ __align__(16) bf16 As[BM][LDSK];
    __shared__ __align__(16) bf16 Bs[BN][LDSK];
    int tid = threadIdx.x;
    int m0 = blockIdx.x * BM;
    int n0 = blockIdx.y * BN;
    int wid = tid >> 6, lane = tid & 63;
    int wm = (wid >> 1) * 64, wn = (wid & 1) * 64;
    int lr = lane & 15;
    int lk = (lane >> 4) * 8;
    int srow = tid >> 2;
    int scol = (tid & 3) * 8;
    f32x4 acc[4][4] = {};
    const bf16* ga0 = A  + (size_t)(m0 + srow)      * K + scol;
    const bf16* ga1 = A  + (size_t)(m0 + 64 + srow) * K + scol;
    const bf16* gb0 = Bt + (size_t)(n0 + srow)      * K + scol;
    const bf16* gb1 = Bt + (size_t)(n0 + 64 + srow) * K + scol;

    for (int k0 = 0; k0 < K; k0 += BK) {
        __syncthreads();
        *(int4*)&As[srow][scol]    = *(const int4*)(ga0 + k0);
        *(int4*)&As[64+srow][scol] = *(const int4*)(ga1 + k0);
        *(int4*)&Bs[srow][scol]    = *(const int4*)(gb0 + k0);
        *(int4*)&Bs[64+srow][scol] = *(const int4*)(gb1 + k0);
        __syncthreads();
        bf16x8 af[4], bfv[4];
        #pragma unroll
        for (int i = 0; i < 4; i++) {
            af[i]  = *(const bf16x8*)&As[wm + i*16 + lr][lk];
            bfv[i] = *(const bf16x8*)&Bs[wn + i*16 + lr][lk];
        }
        #pragma unroll
        for (int i = 0; i < 4; i++)
            #pragma unroll
            for (int j = 0; j < 4; j++)
                acc[i][j] = __builtin_amdgcn_mfma_f32_16x16x32_bf16(af[i], bfv[j], acc[i][j], 0, 0, 0);
    }

    int mrow = 4 * (lane >> 4);
    #pragma unroll
    for (int i = 0; i < 4; i++) {
        #pragma unroll
        for (int j = 0; j < 4; j++) {
            int nb = n0 + wn + j*16 + lr;
            float bb = bias[nb];
            #pragma unroll
            for (int r = 0; r < 4; r++) {
                int m = m0 + wm + i*16 + mrow + r;
                size_t idx = (size_t)m * N + nb;
                float v = acc[i][j][r] + bb;
                if (EPI == 0) {
                    float yv = v / (1.f + __expf(-v));
                    float sxv = e0[idx * (size_t)e0_stride];   // cwp real part
                    outf[idx] = sxv * yv + e1[idx];
                } else if (EPI == 1) {
                    float yv = v / (1.f + __expf(-v));
                    outb[idx] = __float2bfloat16(yv);
                } else {
                    outf[idx] = v + e0[idx];
                }
            }
        }
    }
}

extern "C" void kernel_launch(void* const* d_in, const int* in_sizes, int n_in,
                              void* d_out, int out_size, void* d_ws, size_t ws_size,
                              hipStream_t stream)
{
    const float* x    = (const float*)d_in[0];
    const float* hr   = (const float*)d_in[1];
    const float* hi   = (const float*)d_in[2];
    const float* pini = (const float*)d_in[3];
    const float* phz  = (const float*)d_in[4];
    const float* fcw  = (const float*)d_in[5];
    const float* fcb  = (const float*)d_in[6];
    const float* w1   = (const float*)d_in[7];
    const float* b1   = (const float*)d_in[8];
    const float* w2   = (const float*)d_in[9];
    const float* b2   = (const float*)d_in[10];
    const float* lng  = (const float*)d_in[11];
    const float* lnb  = (const float*)d_in[12];

    float* out = (float*)d_out;
    float* cwp = out + (size_t)NROWS * D_MODEL;
    // Output 1 (conv_with_past, complex64): harness stores either real part only
    // (out_size = 2*NROWS*D) or interleaved re/im (out_size = 3*NROWS*D).
    int interleaved = (out_size >= NROWS * D_MODEL * 3) ? 1 : 0;

    char* ws = (char*)d_ws;
    size_t off = 0;
    bf16*  wfcb = (bf16*)(ws + off);  off += (size_t)D_MODEL*D_MODEL*2;
    bf16*  w1b  = (bf16*)(ws + off);  off += (size_t)D_FF*D_MODEL*2;
    bf16*  w2b  = (bf16*)(ws + off);  off += (size_t)D_MODEL*D_FF*2;
    float* pv   = (float*)(ws + off); off += (size_t)4*D_MODEL*4;
    float* xn   = (float*)(ws + off); off += (size_t)NROWS*D_MODEL*4;
    bf16*  xbf  = (bf16*)(ws + off);  off += (size_t)NROWS*D_MODEL*2;
    float* Sc   = (float*)(ws + off); off += (size_t)NBATCH*NCHUNK*D_MODEL*2*4;
    float* pref = (float*)(ws + off); off += (size_t)NBATCH*NCHUNK*D_MODEL*2*4;
    float* x2   = (float*)(ws + off); off += (size_t)NROWS*D_MODEL*4;
    bf16*  x3b  = (bf16*)(ws + off);  off += (size_t)NROWS*D_MODEL*2;
    bf16*  hbuf = (bf16*)(ws + off);  off += (size_t)NROWS*D_FF*2;

    // weight + input casts to bf16
    cast4<<<1024, 256, 0, stream>>>((const float4*)fcw, (ushort4*)wfcb, D_MODEL*D_MODEL/4);
    cast4<<<4096, 256, 0, stream>>>((const float4*)w1,  (ushort4*)w1b,  D_FF*D_MODEL/4);
    cast4<<<4096, 256, 0, stream>>>((const float4*)w2,  (ushort4*)w2b,  D_MODEL*D_FF/4);
    cast4<<<8192, 256, 0, stream>>>((const float4*)x,   (ushort4*)xbf,  NROWS*D_MODEL/4);

    compute_pvec<<<4, 256, 0, stream>>>(phz, pv);

    // xn = LN(x) in f32 (scan input)
    ln_fused<<<NROWS, 256, 0, stream>>>(x, lng, lnb, xn, nullptr);

    // chunked linear scan: U[l] = p*U[l-1] + init_c*xn[l], U[-1]=hidden; cwp = U
    scan_pass1<<<dim3(4, NCHUNK, NBATCH), 256, 0, stream>>>(xn, pv, pini, Sc);
    scan_prefix<<<dim3(4, NBATCH), 256, 0, stream>>>(Sc, pv, hr, hi, pref);
    scan_pass2<<<dim3(4, NCHUNK, NBATCH), 256, 0, stream>>>(xn, pv, pini, pref, cwp, interleaved);

    // gate: x2 = real(cwp) * silu(x @ fc_w^T + fc_b) + x
    gemm_bt<0><<<dim3(NROWS/BM, D_MODEL/BN), 256, 0, stream>>>(
        xbf, wfcb, fcb, cwp, interleaved ? 2 : 1, x, x2, nullptr, NROWS, D_MODEL, D_MODEL);

    // x3 = LN(x2) -> bf16
    ln_fused<<<NROWS, 256, 0, stream>>>(x2, lng, lnb, nullptr, x3b);

    // h = silu(x3 @ w1^T + b1) -> bf16
    gemm_bt<1><<<dim3(NROWS/BM, D_FF/BN), 256, 0, stream>>>(
        x3b, w1b, b1, nullptr, 1, nullptr, nullptr, hbuf, NROWS, D_FF, D_MODEL);

    // out = h @ w2^T + b2 + x2
    gemm_bt<2><<<dim3(NROWS/BM, D_MODEL/BN), 256, 0, stream>>>(
        hbuf, w2b, b2, x2, 1, nullptr, out, nullptr, NROWS, D_MODEL, D_FF);
}

// Round 4
// 324.156 us; speedup vs baseline: 1.0449x; 1.0449x over previous
//
#include <hip/hip_runtime.h>
#include <hip/hip_bf16.h>

#define D_MODEL 1024
#define D_FF    4096
#define SEQ_LEN 2048
#define NBATCH  4
#define NROWS   (NBATCH*SEQ_LEN)   // 8192
#define NCHUNK  32
#define CHUNK_L (SEQ_LEN/NCHUNK)   // 64
#define LN_EPS  1e-5f

typedef __hip_bfloat16 bf16;
typedef __attribute__((ext_vector_type(8))) short bf16x8;
typedef __attribute__((ext_vector_type(4))) float f32x4;

// async global->LDS, 16B per lane; LDS dest is wave-uniform base + lane*16
__device__ __forceinline__ void gload16(const bf16* g, bf16* l) {
    __builtin_amdgcn_global_load_lds(
        (const __attribute__((address_space(1))) void*)g,
        (__attribute__((address_space(3))) void*)l, 16, 0, 0);
}

// ---------------- cast f32 -> bf16, vectorized ----------------
__global__ void cast4(const float4* __restrict__ in, ushort4* __restrict__ out, int n4) {
    int i = blockIdx.x * blockDim.x + threadIdx.x;
    if (i < n4) {
        float4 v = in[i];
        union { ushort4 u; bf16 b[4]; } cv;
        cv.b[0] = __float2bfloat16(v.x); cv.b[1] = __float2bfloat16(v.y);
        cv.b[2] = __float2bfloat16(v.z); cv.b[3] = __float2bfloat16(v.w);
        out[i] = cv.u;
    }
}

// ---------------- p, p^64 from phazor ----------------
__global__ void compute_pvec(const float* __restrict__ phz, float* __restrict__ pv) {
    int d = blockIdx.x * blockDim.x + threadIdx.x;
    if (d >= D_MODEL) return;
    float re = phz[2*d], im = phz[2*d+1];
    float r2 = re*re + im*im;
    float mag = expf(-r2);
    float pr, pim;
    if (r2 > 0.f) { float inv = mag / sqrtf(r2); pr = re*inv; pim = im*inv; }
    else          { pr = mag; pim = 0.f; }
    float ar = pr, ai = pim;
    #pragma unroll
    for (int i = 0; i < 6; i++) { float nr = ar*ar - ai*ai; float ni = 2.f*ar*ai; ar = nr; ai = ni; }
    pv[d]            = pr;
    pv[D_MODEL+d]    = pim;
    pv[2*D_MODEL+d]  = ar;
    pv[3*D_MODEL+d]  = ai;
}

// ---------------- LayerNorm (+ optional raw-x bf16 cast output) ----------------
__global__ __launch_bounds__(256) void ln_fused(const float* __restrict__ x,
                                                const float* __restrict__ g,
                                                const float* __restrict__ bta,
                                                float* __restrict__ outf,
                                                bf16*  __restrict__ outb,
                                                bf16*  __restrict__ rawb)
{
    int row = blockIdx.x;
    int tid = threadIdx.x;
    const float4* xr = (const float4*)(x + (size_t)row * D_MODEL);
    float4 v = xr[tid];
    if (rawb) {
        union { ushort4 u; bf16 b[4]; } cv;
        cv.b[0]=__float2bfloat16(v.x); cv.b[1]=__float2bfloat16(v.y);
        cv.b[2]=__float2bfloat16(v.z); cv.b[3]=__float2bfloat16(v.w);
        ((ushort4*)(rawb + (size_t)row * D_MODEL))[tid] = cv.u;
    }
    float s  = v.x + v.y + v.z + v.w;
    float s2 = v.x*v.x + v.y*v.y + v.z*v.z + v.w*v.w;
    for (int off = 32; off; off >>= 1) { s += __shfl_down(s, off); s2 += __shfl_down(s2, off); }
    __shared__ float red[8];
    int wid = tid >> 6, lane = tid & 63;
    if (lane == 0) { red[wid] = s; red[4+wid] = s2; }
    __syncthreads();
    if (tid == 0) {
        red[0] = red[0]+red[1]+red[2]+red[3];
        red[4] = red[4]+red[5]+red[6]+red[7];
    }
    __syncthreads();
    float mu  = red[0] * (1.f/D_MODEL);
    float var = red[4] * (1.f/D_MODEL) - mu*mu;
    float rstd = rsqrtf(var + LN_EPS);
    float4 gv = ((const float4*)g)[tid];
    float4 bv = ((const float4*)bta)[tid];
    float4 o;
    o.x = (v.x-mu)*rstd*gv.x + bv.x;
    o.y = (v.y-mu)*rstd*gv.y + bv.y;
    o.z = (v.z-mu)*rstd*gv.z + bv.z;
    o.w = (v.w-mu)*rstd*gv.w + bv.w;
    if (outf) ((float4*)(outf + (size_t)row * D_MODEL))[tid] = o;
    if (outb) {
        union { ushort4 u; bf16 b[4]; } cv;
        cv.b[0]=__float2bfloat16(o.x); cv.b[1]=__float2bfloat16(o.y);
        cv.b[2]=__float2bfloat16(o.z); cv.b[3]=__float2bfloat16(o.w);
        ((ushort4*)(outb + (size_t)row * D_MODEL))[tid] = cv.u;
    }
}

// ---------------- scan pass 1: per-chunk local state (zero init) ----------------
__global__ __launch_bounds__(256) void scan_pass1(const float* __restrict__ xn,
                                                  const float* __restrict__ pv,
                                                  const float* __restrict__ pini,
                                                  float* __restrict__ Sc)
{
    int d = blockIdx.x * 256 + threadIdx.x;
    int c = blockIdx.y, b = blockIdx.z;
    float pr = pv[d], pim = pv[D_MODEL+d];
    float icr = pini[2*d], ici = pini[2*d+1];
    float Sr = 0.f, Si = 0.f;
    const float* xp = xn + ((size_t)b*SEQ_LEN + c*CHUNK_L) * D_MODEL + d;
    #pragma unroll 8
    for (int i = 0; i < CHUNK_L; i++) {
        float xv = xp[(size_t)i * D_MODEL];
        float nr = pr*Sr - pim*Si + icr*xv;
        float ni = pr*Si + pim*Sr + ici*xv;
        Sr = nr; Si = ni;
    }
    size_t o = ((size_t)b*NCHUNK + c) * D_MODEL + d;
    Sc[2*o] = Sr; Sc[2*o+1] = Si;
}

// ---------------- scan pass 2: exclusive prefix over chunks (init = hidden) ----------------
__global__ __launch_bounds__(256) void scan_prefix(const float* __restrict__ Sc,
                                                   const float* __restrict__ pv,
                                                   const float* __restrict__ hr,
                                                   const float* __restrict__ hi,
                                                   float* __restrict__ pref)
{
    int d = blockIdx.x * 256 + threadIdx.x;
    int b = blockIdx.y;
    float qr = pv[2*D_MODEL+d], qi = pv[3*D_MODEL+d];   // p^64
    float Ur = hr[b*D_MODEL+d], Ui = hi[b*D_MODEL+d];
    for (int c = 0; c < NCHUNK; c++) {
        size_t o = ((size_t)b*NCHUNK + c) * D_MODEL + d;
        pref[2*o] = Ur; pref[2*o+1] = Ui;
        float sr = Sc[2*o], si = Sc[2*o+1];
        float nr = qr*Ur - qi*Ui + sr;
        float ni = qr*Ui + qi*Ur + si;
        Ur = nr; Ui = ni;
    }
}

// ---------------- scan pass 3: final states, write conv_with_past ----------------
__global__ __launch_bounds__(256) void scan_pass2(const float* __restrict__ xn,
                                                  const float* __restrict__ pv,
                                                  const float* __restrict__ pini,
                                                  const float* __restrict__ pref,
                                                  float* __restrict__ cwp,
                                                  int interleaved)
{
    int d = blockIdx.x * 256 + threadIdx.x;
    int c = blockIdx.y, b = blockIdx.z;
    float pr = pv[d], pim = pv[D_MODEL+d];
    float icr = pini[2*d], ici = pini[2*d+1];
    size_t po = ((size_t)b*NCHUNK + c) * D_MODEL + d;
    float Ur = pref[2*po], Ui = pref[2*po+1];
    size_t base = ((size_t)b*SEQ_LEN + c*CHUNK_L) * D_MODEL + d;
    const float* xp = xn + base;
    if (interleaved) {
        float2* cp = (float2*)cwp + base;
        #pragma unroll 8
        for (int i = 0; i < CHUNK_L; i++) {
            float xv = xp[(size_t)i * D_MODEL];
            float nr = pr*Ur - pim*Ui + icr*xv;
            float ni = pr*Ui + pim*Ur + ici*xv;
            Ur = nr; Ui = ni;
            cp[(size_t)i * D_MODEL] = make_float2(Ur, Ui);
        }
    } else {
        float* cp = cwp + base;
        #pragma unroll 8
        for (int i = 0; i < CHUNK_L; i++) {
            float xv = xp[(size_t)i * D_MODEL];
            float nr = pr*Ur - pim*Ui + icr*xv;
            float ni = pr*Ui + pim*Ur + ici*xv;
            Ur = nr; Ui = ni;
            cp[(size_t)i * D_MODEL] = Ur;
        }
    }
}

// ---------------- bf16 MFMA GEMM, global_load_lds staging, swizzled LDS ----------------
// LDS layout: linear [128][32] bf16 (64B rows). Physical 16B chunk c_phys of row r
// holds logical k-chunk c_phys ^ ((r>>1)&3)  (both-sides swizzle: pre-swizzled global
// source at stage time + same XOR on ds_read address; spreads 16 fragment rows over
// all 8 line positions -> 2-way (free) instead of 8-way).
// EPI 0: x2 = cwp_real * silu(acc + bias) + x_res   (writes f32)
// EPI 1: h  = silu(acc + bias)                      (writes bf16)
// EPI 2: out = acc + bias + x2                      (writes f32)
#define BM 128
#define BN 128
#define BK 32

template<int EPI>
__global__ __launch_bounds__(256) void gemm_bt(const bf16* __restrict__ A,
                                               const bf16* __restrict__ Bt,
                                               const float* __restrict__ bias,
                                               const float* __restrict__ e0, int e0_stride,
                                               const float* __restrict__ e1,
                                               float* __restrict__ outf,
                                               bf16*  __restrict__ outb,
                                               int M, int N, int K)
{
    __shared__ __align__(16) bf16 As[BM*BK];
    __shared__ __align__(16) bf16 Bs[BN*BK];
    int tid = threadIdx.x;
    int m0 = blockIdx.x * BM;
    int n0 = blockIdx.y * BN;
    int wid = tid >> 6, lane = tid & 63;
    int wm = (wid >> 1) * 64, wn = (wid & 1) * 64;
    int lr = lane & 15;
    int lkc = lane >> 4;           // logical k-chunk 0..3 (k = lkc*8)

    // --- staging addresses: wave w stages rows [w*16, w*16+16) and [64+w*16, ...)
    // lane l covers (row = base + (l>>2), phys chunk = l&3); fetch logical chunk
    // (l&3) ^ key(row), key(row) = (row>>1)&3 = ((l>>2)>>1)&3.
    int rl = lane >> 2;
    int cS = (lane & 3) ^ ((rl >> 1) & 3);
    const bf16* gA0 = A  + (size_t)(m0 +      wid*16 + rl) * K + cS*8;
    const bf16* gA1 = A  + (size_t)(m0 + 64 + wid*16 + rl) * K + cS*8;
    const bf16* gB0 = Bt + (size_t)(n0 +      wid*16 + rl) * K + cS*8;
    const bf16* gB1 = Bt + (size_t)(n0 + 64 + wid*16 + rl) * K + cS*8;
    bf16* lA0 = &As[(     wid*16) * BK];
    bf16* lA1 = &As[(64 + wid*16) * BK];
    bf16* lB0 = &Bs[(     wid*16) * BK];
    bf16* lB1 = &Bs[(64 + wid*16) * BK];

    // --- fragment read offsets (elements), swizzled
    int keyr = (lr >> 1) & 3;
    int cR = (lkc ^ keyr) * 8;
    int offA[4], offB[4];
    #pragma unroll
    for (int i = 0; i < 4; i++) {
        offA[i] = (wm + i*16 + lr) * BK + cR;
        offB[i] = (wn + i*16 + lr) * BK + cR;
    }

    f32x4 acc[4][4] = {};
    for (int k0 = 0; k0 < K; k0 += BK) {
        __syncthreads();                    // all waves done reading previous tile
        gload16(gA0 + k0, lA0);
        gload16(gA1 + k0, lA1);
        gload16(gB0 + k0, lB0);
        gload16(gB1 + k0, lB1);
        __syncthreads();                    // compiler drains vmcnt(0) before barrier
        bf16x8 af[4], bfv[4];
        #pragma unroll
        for (int i = 0; i < 4; i++) {
            af[i]  = *(const bf16x8*)&As[offA[i]];
            bfv[i] = *(const bf16x8*)&Bs[offB[i]];
        }
        #pragma unroll
        for (int i = 0; i < 4; i++)
            #pragma unroll
            for (int j = 0; j < 4; j++)
                acc[i][j] = __builtin_amdgcn_mfma_f32_16x16x32_bf16(af[i], bfv[j], acc[i][j], 0, 0, 0);
    }

    int mrow = 4 * (lane >> 4);
    #pragma unroll
    for (int i = 0; i < 4; i++) {
        #pragma unroll
        for (int j = 0; j < 4; j++) {
            int nb = n0 + wn + j*16 + lr;
            float bb = bias[nb];
            #pragma unroll
            for (int r = 0; r < 4; r++) {
                int m = m0 + wm + i*16 + mrow + r;
                size_t idx = (size_t)m * N + nb;
                float v = acc[i][j][r] + bb;
                if (EPI == 0) {
                    float yv = v / (1.f + __expf(-v));
                    float sxv = e0[idx * (size_t)e0_stride];   // cwp real part
                    outf[idx] = sxv * yv + e1[idx];
                } else if (EPI == 1) {
                    float yv = v / (1.f + __expf(-v));
                    outb[idx] = __float2bfloat16(yv);
                } else {
                    outf[idx] = v + e0[idx];
                }
            }
        }
    }
}

extern "C" void kernel_launch(void* const* d_in, const int* in_sizes, int n_in,
                              void* d_out, int out_size, void* d_ws, size_t ws_size,
                              hipStream_t stream)
{
    const float* x    = (const float*)d_in[0];
    const float* hr   = (const float*)d_in[1];
    const float* hi   = (const float*)d_in[2];
    const float* pini = (const float*)d_in[3];
    const float* phz  = (const float*)d_in[4];
    const float* fcw  = (const float*)d_in[5];
    const float* fcb  = (const float*)d_in[6];
    const float* w1   = (const float*)d_in[7];
    const float* b1   = (const float*)d_in[8];
    const float* w2   = (const float*)d_in[9];
    const float* b2   = (const float*)d_in[10];
    const float* lng  = (const float*)d_in[11];
    const float* lnb  = (const float*)d_in[12];

    float* out = (float*)d_out;
    float* cwp = out + (size_t)NROWS * D_MODEL;
    int interleaved = (out_size >= NROWS * D_MODEL * 3) ? 1 : 0;

    char* ws = (char*)d_ws;
    size_t off = 0;
    bf16*  wfcb = (bf16*)(ws + off);  off += (size_t)D_MODEL*D_MODEL*2;
    bf16*  w1b  = (bf16*)(ws + off);  off += (size_t)D_FF*D_MODEL*2;
    bf16*  w2b  = (bf16*)(ws + off);  off += (size_t)D_MODEL*D_FF*2;
    float* pv   = (float*)(ws + off); off += (size_t)4*D_MODEL*4;
    float* xn   = (float*)(ws + off); off += (size_t)NROWS*D_MODEL*4;
    bf16*  xbf  = (bf16*)(ws + off);  off += (size_t)NROWS*D_MODEL*2;
    float* Sc   = (float*)(ws + off); off += (size_t)NBATCH*NCHUNK*D_MODEL*2*4;
    float* pref = (float*)(ws + off); off += (size_t)NBATCH*NCHUNK*D_MODEL*2*4;
    float* x2   = (float*)(ws + off); off += (size_t)NROWS*D_MODEL*4;
    bf16*  x3b  = (bf16*)(ws + off);  off += (size_t)NROWS*D_MODEL*2;
    bf16*  hbuf = (bf16*)(ws + off);  off += (size_t)NROWS*D_FF*2;

    // weight casts to bf16 (x cast is fused into the first LayerNorm)
    cast4<<<1024, 256, 0, stream>>>((const float4*)fcw, (ushort4*)wfcb, D_MODEL*D_MODEL/4);
    cast4<<<4096, 256, 0, stream>>>((const float4*)w1,  (ushort4*)w1b,  D_FF*D_MODEL/4);
    cast4<<<4096, 256, 0, stream>>>((const float4*)w2,  (ushort4*)w2b,  D_MODEL*D_FF/4);

    compute_pvec<<<4, 256, 0, stream>>>(phz, pv);

    // xn = LN(x) in f32 (scan input); also xbf = bf16(x) for the gate GEMM
    ln_fused<<<NROWS, 256, 0, stream>>>(x, lng, lnb, xn, nullptr, xbf);

    // chunked linear scan: U[l] = p*U[l-1] + init_c*xn[l], U[-1]=hidden; cwp = U
    scan_pass1<<<dim3(4, NCHUNK, NBATCH), 256, 0, stream>>>(xn, pv, pini, Sc);
    scan_prefix<<<dim3(4, NBATCH), 256, 0, stream>>>(Sc, pv, hr, hi, pref);
    scan_pass2<<<dim3(4, NCHUNK, NBATCH), 256, 0, stream>>>(xn, pv, pini, pref, cwp, interleaved);

    // gate: x2 = real(cwp) * silu(x @ fc_w^T + fc_b) + x
    gemm_bt<0><<<dim3(NROWS/BM, D_MODEL/BN), 256, 0, stream>>>(
        xbf, wfcb, fcb, cwp, interleaved ? 2 : 1, x, x2, nullptr, NROWS, D_MODEL, D_MODEL);

    // x3 = LN(x2) -> bf16
    ln_fused<<<NROWS, 256, 0, stream>>>(x2, lng, lnb, nullptr, x3b, nullptr);

    // h = silu(x3 @ w1^T + b1) -> bf16
    gemm_bt<1><<<dim3(NROWS/BM, D_FF/BN), 256, 0, stream>>>(
        x3b, w1b, b1, nullptr, 1, nullptr, nullptr, hbuf, NROWS, D_FF, D_MODEL);

    // out = h @ w2^T + b2 + x2
    gemm_bt<2><<<dim3(NROWS/BM, D_MODEL/BN), 256, 0, stream>>>(
        hbuf, w2b, b2, x2, 1, nullptr, out, nullptr, NROWS, D_MODEL, D_FF);
}

// Round 5
// 316.182 us; speedup vs baseline: 1.0712x; 1.0252x over previous
//
#include <hip/hip_runtime.h>
#include <hip/hip_bf16.h>

#define D_MODEL 1024
#define D_FF    4096
#define SEQ_LEN 2048
#define NBATCH  4
#define NROWS   (NBATCH*SEQ_LEN)   // 8192
#define NCHUNK  32
#define CHUNK_L (SEQ_LEN/NCHUNK)   // 64
#define LN_EPS  1e-5f

typedef __hip_bfloat16 bf16;
typedef __attribute__((ext_vector_type(8))) short bf16x8;
typedef __attribute__((ext_vector_type(4))) float f32x4;

// async global->LDS, 16B per lane; LDS dest is wave-uniform base + lane*16
__device__ __forceinline__ void gload16(const bf16* g, bf16* l) {
    __builtin_amdgcn_global_load_lds(
        (const __attribute__((address_space(1))) void*)g,
        (__attribute__((address_space(3))) void*)l, 16, 0, 0);
}

// ---------------- cast f32 -> bf16, vectorized ----------------
__global__ void cast4(const float4* __restrict__ in, ushort4* __restrict__ out, int n4) {
    int i = blockIdx.x * blockDim.x + threadIdx.x;
    if (i < n4) {
        float4 v = in[i];
        union { ushort4 u; bf16 b[4]; } cv;
        cv.b[0] = __float2bfloat16(v.x); cv.b[1] = __float2bfloat16(v.y);
        cv.b[2] = __float2bfloat16(v.z); cv.b[3] = __float2bfloat16(v.w);
        out[i] = cv.u;
    }
}

// ---------------- p, p^64 from phazor ----------------
__global__ void compute_pvec(const float* __restrict__ phz, float* __restrict__ pv) {
    int d = blockIdx.x * blockDim.x + threadIdx.x;
    if (d >= D_MODEL) return;
    float re = phz[2*d], im = phz[2*d+1];
    float r2 = re*re + im*im;
    float mag = expf(-r2);
    float pr, pim;
    if (r2 > 0.f) { float inv = mag / sqrtf(r2); pr = re*inv; pim = im*inv; }
    else          { pr = mag; pim = 0.f; }
    float ar = pr, ai = pim;
    #pragma unroll
    for (int i = 0; i < 6; i++) { float nr = ar*ar - ai*ai; float ni = 2.f*ar*ai; ar = nr; ai = ni; }
    pv[d]            = pr;
    pv[D_MODEL+d]    = pim;
    pv[2*D_MODEL+d]  = ar;
    pv[3*D_MODEL+d]  = ai;
}

// ---------------- LayerNorm (+ optional raw-x bf16 cast output) ----------------
__global__ __launch_bounds__(256) void ln_fused(const float* __restrict__ x,
                                                const float* __restrict__ g,
                                                const float* __restrict__ bta,
                                                float* __restrict__ outf,
                                                bf16*  __restrict__ outb,
                                                bf16*  __restrict__ rawb)
{
    int row = blockIdx.x;
    int tid = threadIdx.x;
    const float4* xr = (const float4*)(x + (size_t)row * D_MODEL);
    float4 v = xr[tid];
    if (rawb) {
        union { ushort4 u; bf16 b[4]; } cv;
        cv.b[0]=__float2bfloat16(v.x); cv.b[1]=__float2bfloat16(v.y);
        cv.b[2]=__float2bfloat16(v.z); cv.b[3]=__float2bfloat16(v.w);
        ((ushort4*)(rawb + (size_t)row * D_MODEL))[tid] = cv.u;
    }
    float s  = v.x + v.y + v.z + v.w;
    float s2 = v.x*v.x + v.y*v.y + v.z*v.z + v.w*v.w;
    for (int off = 32; off; off >>= 1) { s += __shfl_down(s, off); s2 += __shfl_down(s2, off); }
    __shared__ float red[8];
    int wid = tid >> 6, lane = tid & 63;
    if (lane == 0) { red[wid] = s; red[4+wid] = s2; }
    __syncthreads();
    if (tid == 0) {
        red[0] = red[0]+red[1]+red[2]+red[3];
        red[4] = red[4]+red[5]+red[6]+red[7];
    }
    __syncthreads();
    float mu  = red[0] * (1.f/D_MODEL);
    float var = red[4] * (1.f/D_MODEL) - mu*mu;
    float rstd = rsqrtf(var + LN_EPS);
    float4 gv = ((const float4*)g)[tid];
    float4 bv = ((const float4*)bta)[tid];
    float4 o;
    o.x = (v.x-mu)*rstd*gv.x + bv.x;
    o.y = (v.y-mu)*rstd*gv.y + bv.y;
    o.z = (v.z-mu)*rstd*gv.z + bv.z;
    o.w = (v.w-mu)*rstd*gv.w + bv.w;
    if (outf) ((float4*)(outf + (size_t)row * D_MODEL))[tid] = o;
    if (outb) {
        union { ushort4 u; bf16 b[4]; } cv;
        cv.b[0]=__float2bfloat16(o.x); cv.b[1]=__float2bfloat16(o.y);
        cv.b[2]=__float2bfloat16(o.z); cv.b[3]=__float2bfloat16(o.w);
        ((ushort4*)(outb + (size_t)row * D_MODEL))[tid] = cv.u;
    }
}

// ---------------- scan pass 1: per-chunk local state (zero init) ----------------
__global__ __launch_bounds__(256) void scan_pass1(const float* __restrict__ xn,
                                                  const float* __restrict__ pv,
                                                  const float* __restrict__ pini,
                                                  float* __restrict__ Sc)
{
    int d = blockIdx.x * 256 + threadIdx.x;
    int c = blockIdx.y, b = blockIdx.z;
    float pr = pv[d], pim = pv[D_MODEL+d];
    float icr = pini[2*d], ici = pini[2*d+1];
    float Sr = 0.f, Si = 0.f;
    const float* xp = xn + ((size_t)b*SEQ_LEN + c*CHUNK_L) * D_MODEL + d;
    #pragma unroll 8
    for (int i = 0; i < CHUNK_L; i++) {
        float xv = xp[(size_t)i * D_MODEL];
        float nr = pr*Sr - pim*Si + icr*xv;
        float ni = pr*Si + pim*Sr + ici*xv;
        Sr = nr; Si = ni;
    }
    size_t o = ((size_t)b*NCHUNK + c) * D_MODEL + d;
    Sc[2*o] = Sr; Sc[2*o+1] = Si;
}

// ---------------- scan pass 2: exclusive prefix over chunks (init = hidden) ----------------
__global__ __launch_bounds__(256) void scan_prefix(const float* __restrict__ Sc,
                                                   const float* __restrict__ pv,
                                                   const float* __restrict__ hr,
                                                   const float* __restrict__ hi,
                                                   float* __restrict__ pref)
{
    int d = blockIdx.x * 256 + threadIdx.x;
    int b = blockIdx.y;
    float qr = pv[2*D_MODEL+d], qi = pv[3*D_MODEL+d];   // p^64
    float Ur = hr[b*D_MODEL+d], Ui = hi[b*D_MODEL+d];
    for (int c = 0; c < NCHUNK; c++) {
        size_t o = ((size_t)b*NCHUNK + c) * D_MODEL + d;
        pref[2*o] = Ur; pref[2*o+1] = Ui;
        float sr = Sc[2*o], si = Sc[2*o+1];
        float nr = qr*Ur - qi*Ui + sr;
        float ni = qr*Ui + qi*Ur + si;
        Ur = nr; Ui = ni;
    }
}

// ---------------- scan pass 3: final states, write conv_with_past ----------------
__global__ __launch_bounds__(256) void scan_pass2(const float* __restrict__ xn,
                                                  const float* __restrict__ pv,
                                                  const float* __restrict__ pini,
                                                  const float* __restrict__ pref,
                                                  float* __restrict__ cwp,
                                                  int interleaved)
{
    int d = blockIdx.x * 256 + threadIdx.x;
    int c = blockIdx.y, b = blockIdx.z;
    float pr = pv[d], pim = pv[D_MODEL+d];
    float icr = pini[2*d], ici = pini[2*d+1];
    size_t po = ((size_t)b*NCHUNK + c) * D_MODEL + d;
    float Ur = pref[2*po], Ui = pref[2*po+1];
    size_t base = ((size_t)b*SEQ_LEN + c*CHUNK_L) * D_MODEL + d;
    const float* xp = xn + base;
    if (interleaved) {
        float2* cp = (float2*)cwp + base;
        #pragma unroll 8
        for (int i = 0; i < CHUNK_L; i++) {
            float xv = xp[(size_t)i * D_MODEL];
            float nr = pr*Ur - pim*Ui + icr*xv;
            float ni = pr*Ui + pim*Ur + ici*xv;
            Ur = nr; Ui = ni;
            cp[(size_t)i * D_MODEL] = make_float2(Ur, Ui);
        }
    } else {
        float* cp = cwp + base;
        #pragma unroll 8
        for (int i = 0; i < CHUNK_L; i++) {
            float xv = xp[(size_t)i * D_MODEL];
            float nr = pr*Ur - pim*Ui + icr*xv;
            float ni = pr*Ui + pim*Ur + ici*xv;
            Ur = nr; Ui = ni;
            cp[(size_t)i * D_MODEL] = Ur;
        }
    }
}

// ---------------- bf16 MFMA GEMM: depth-3 LDS pipeline, counted vmcnt ----------------
// LDS: 3 rotating slots of linear [128][32] bf16. Both-sides chunk swizzle
// (phys chunk = logical ^ ((row>>1)&3)) via pre-swizzled global source + same
// XOR on ds_read address (0 bank conflicts, verified round 4).
// Pipeline: prologue stages tiles 0..2; iter t waits vmcnt(8) (oldest slot's 4
// loads done), raw s_barrier (NO vmcnt(0) drain), ds_read+MFMA, barrier,
// re-stage slot with tile t+3 (wrapped mod nt so vmcnt stays literal).
// EPI 0: x2 = cwp_real * silu(acc + bias) + x_res   (writes f32)
// EPI 1: h  = silu(acc + bias)                      (writes bf16)
// EPI 2: out = acc + bias + x2                      (writes f32)
#define BM 128
#define BN 128
#define BK 32

template<int EPI>
__global__ __launch_bounds__(256) void gemm_bt(const bf16* __restrict__ A,
                                               const bf16* __restrict__ Bt,
                                               const float* __restrict__ bias,
                                               const float* __restrict__ e0, int e0_stride,
                                               const float* __restrict__ e1,
                                               float* __restrict__ outf,
                                               bf16*  __restrict__ outb,
                                               int M, int N, int K)
{
    __shared__ __align__(16) bf16 As[3][BM*BK];
    __shared__ __align__(16) bf16 Bs[3][BM*BK];
    int tid = threadIdx.x;

    // XCD-aware swizzle: each XCD gets a contiguous chunk of logical tile space
    // (x fastest) so its blocks share B-panels -> L2-resident. All grids %8==0.
    int nwg = gridDim.x * gridDim.y;
    int id  = blockIdx.x + gridDim.x * blockIdx.y;
    int cpx = nwg >> 3;
    int sw  = (id & 7) * cpx + (id >> 3);
    int m0  = (sw % gridDim.x) * BM;
    int n0  = (sw / gridDim.x) * BN;

    int wid = tid >> 6, lane = tid & 63;
    int wm = (wid >> 1) * 64, wn = (wid & 1) * 64;
    int lr = lane & 15;
    int lkc = lane >> 4;           // logical k-chunk 0..3

    // staging: wave w covers rows [w*16,w*16+16) and [64+w*16,...); lane l ->
    // (row = l>>2, phys chunk = l&3), fetch logical chunk (l&3)^((row>>1)&3).
    int rl = lane >> 2;
    int cS = (lane & 3) ^ ((rl >> 1) & 3);
    const bf16* gA0 = A  + (size_t)(m0 +      wid*16 + rl) * K + cS*8;
    const bf16* gA1 = A  + (size_t)(m0 + 64 + wid*16 + rl) * K + cS*8;
    const bf16* gB0 = Bt + (size_t)(n0 +      wid*16 + rl) * K + cS*8;
    const bf16* gB1 = Bt + (size_t)(n0 + 64 + wid*16 + rl) * K + cS*8;
    int lo0 = (     wid*16) * BK;
    int lo1 = (64 + wid*16) * BK;

    // fragment read offsets (elements within a slot), swizzled
    int keyr = (lr >> 1) & 3;
    int cR = (lkc ^ keyr) * 8;
    int offA[4], offB[4];
    #pragma unroll
    for (int i = 0; i < 4; i++) {
        offA[i] = (wm + i*16 + lr) * BK + cR;
        offB[i] = (wn + i*16 + lr) * BK + cR;
    }

    int nt = K / BK;   // 32 or 128, always >= 3
    auto stage = [&](int slot, int tile) {
        int k0 = tile * BK;
        gload16(gA0 + k0, &As[slot][lo0]);
        gload16(gA1 + k0, &As[slot][lo1]);
        gload16(gB0 + k0, &Bs[slot][lo0]);
        gload16(gB1 + k0, &Bs[slot][lo1]);
    };
    stage(0, 0); stage(1, 1); stage(2, 2);   // 12 loads in flight

    f32x4 acc[4][4] = {};
    int s = 0;
    for (int t = 0; t < nt; ++t) {
        // oldest slot's 4 loads complete when <=8 remain outstanding
        asm volatile("s_waitcnt vmcnt(8)" ::: "memory");
        __builtin_amdgcn_s_barrier();            // all waves' slot-s loads landed
        __builtin_amdgcn_sched_barrier(0);
        bf16x8 af[4], bfv[4];
        #pragma unroll
        for (int i = 0; i < 4; i++) {
            af[i]  = *(const bf16x8*)&As[s][offA[i]];
            bfv[i] = *(const bf16x8*)&Bs[s][offB[i]];
        }
        #pragma unroll
        for (int i = 0; i < 4; i++)
            #pragma unroll
            for (int j = 0; j < 4; j++)
                acc[i][j] = __builtin_amdgcn_mfma_f32_16x16x32_bf16(af[i], bfv[j], acc[i][j], 0, 0, 0);
        asm volatile("" ::: "memory");           // pin ds_reads above the barrier
        __builtin_amdgcn_s_barrier();            // all waves done reading slot s
        int nxt = t + 3; if (nxt >= nt) nxt -= nt;   // wrap: uniform vmcnt, dead stages never read
        stage(s, nxt);
        s = (s == 2) ? 0 : s + 1;
    }
    asm volatile("s_waitcnt vmcnt(0)" ::: "memory");  // drain LDS-DMA before exit

    int mrow = 4 * (lane >> 4);
    #pragma unroll
    for (int i = 0; i < 4; i++) {
        #pragma unroll
        for (int j = 0; j < 4; j++) {
            int nb = n0 + wn + j*16 + lr;
            float bb = bias[nb];
            #pragma unroll
            for (int r = 0; r < 4; r++) {
                int m = m0 + wm + i*16 + mrow + r;
                size_t idx = (size_t)m * N + nb;
                float v = acc[i][j][r] + bb;
                if (EPI == 0) {
                    float yv = v / (1.f + __expf(-v));
                    float sxv = e0[idx * (size_t)e0_stride];   // cwp real part
                    outf[idx] = sxv * yv + e1[idx];
                } else if (EPI == 1) {
                    float yv = v / (1.f + __expf(-v));
                    outb[idx] = __float2bfloat16(yv);
                } else {
                    outf[idx] = v + e0[idx];
                }
            }
        }
    }
}

extern "C" void kernel_launch(void* const* d_in, const int* in_sizes, int n_in,
                              void* d_out, int out_size, void* d_ws, size_t ws_size,
                              hipStream_t stream)
{
    const float* x    = (const float*)d_in[0];
    const float* hr   = (const float*)d_in[1];
    const float* hi   = (const float*)d_in[2];
    const float* pini = (const float*)d_in[3];
    const float* phz  = (const float*)d_in[4];
    const float* fcw  = (const float*)d_in[5];
    const float* fcb  = (const float*)d_in[6];
    const float* w1   = (const float*)d_in[7];
    const float* b1   = (const float*)d_in[8];
    const float* w2   = (const float*)d_in[9];
    const float* b2   = (const float*)d_in[10];
    const float* lng  = (const float*)d_in[11];
    const float* lnb  = (const float*)d_in[12];

    float* out = (float*)d_out;
    float* cwp = out + (size_t)NROWS * D_MODEL;
    int interleaved = (out_size >= NROWS * D_MODEL * 3) ? 1 : 0;

    char* ws = (char*)d_ws;
    size_t off = 0;
    bf16*  wfcb = (bf16*)(ws + off);  off += (size_t)D_MODEL*D_MODEL*2;
    bf16*  w1b  = (bf16*)(ws + off);  off += (size_t)D_FF*D_MODEL*2;
    bf16*  w2b  = (bf16*)(ws + off);  off += (size_t)D_MODEL*D_FF*2;
    float* pv   = (float*)(ws + off); off += (size_t)4*D_MODEL*4;
    float* xn   = (float*)(ws + off); off += (size_t)NROWS*D_MODEL*4;
    bf16*  xbf  = (bf16*)(ws + off);  off += (size_t)NROWS*D_MODEL*2;
    float* Sc   = (float*)(ws + off); off += (size_t)NBATCH*NCHUNK*D_MODEL*2*4;
    float* pref = (float*)(ws + off); off += (size_t)NBATCH*NCHUNK*D_MODEL*2*4;
    float* x2   = (float*)(ws + off); off += (size_t)NROWS*D_MODEL*4;
    bf16*  x3b  = (bf16*)(ws + off);  off += (size_t)NROWS*D_MODEL*2;
    bf16*  hbuf = (bf16*)(ws + off);  off += (size_t)NROWS*D_FF*2;

    // weight casts to bf16 (x cast is fused into the first LayerNorm)
    cast4<<<1024, 256, 0, stream>>>((const float4*)fcw, (ushort4*)wfcb, D_MODEL*D_MODEL/4);
    cast4<<<4096, 256, 0, stream>>>((const float4*)w1,  (ushort4*)w1b,  D_FF*D_MODEL/4);
    cast4<<<4096, 256, 0, stream>>>((const float4*)w2,  (ushort4*)w2b,  D_MODEL*D_FF/4);

    compute_pvec<<<4, 256, 0, stream>>>(phz, pv);

    // xn = LN(x) in f32 (scan input); also xbf = bf16(x) for the gate GEMM
    ln_fused<<<NROWS, 256, 0, stream>>>(x, lng, lnb, xn, nullptr, xbf);

    // chunked linear scan: U[l] = p*U[l-1] + init_c*xn[l], U[-1]=hidden; cwp = U
    scan_pass1<<<dim3(4, NCHUNK, NBATCH), 256, 0, stream>>>(xn, pv, pini, Sc);
    scan_prefix<<<dim3(4, NBATCH), 256, 0, stream>>>(Sc, pv, hr, hi, pref);
    scan_pass2<<<dim3(4, NCHUNK, NBATCH), 256, 0, stream>>>(xn, pv, pini, pref, cwp, interleaved);

    // gate: x2 = real(cwp) * silu(x @ fc_w^T + fc_b) + x
    gemm_bt<0><<<dim3(NROWS/BM, D_MODEL/BN), 256, 0, stream>>>(
        xbf, wfcb, fcb, cwp, interleaved ? 2 : 1, x, x2, nullptr, NROWS, D_MODEL, D_MODEL);

    // x3 = LN(x2) -> bf16
    ln_fused<<<NROWS, 256, 0, stream>>>(x2, lng, lnb, nullptr, x3b, nullptr);

    // h = silu(x3 @ w1^T + b1) -> bf16
    gemm_bt<1><<<dim3(NROWS/BM, D_FF/BN), 256, 0, stream>>>(
        x3b, w1b, b1, nullptr, 1, nullptr, nullptr, hbuf, NROWS, D_FF, D_MODEL);

    // out = h @ w2^T + b2 + x2
    gemm_bt<2><<<dim3(NROWS/BM, D_MODEL/BN), 256, 0, stream>>>(
        hbuf, w2b, b2, x2, 1, nullptr, out, nullptr, NROWS, D_MODEL, D_FF);
}

// Round 6
// 274.711 us; speedup vs baseline: 1.2329x; 1.1510x over previous
//
#include <hip/hip_runtime.h>
#include <hip/hip_bf16.h>

#define D_MODEL 1024
#define D_FF    4096
#define SEQ_LEN 2048
#define NBATCH  4
#define NROWS   (NBATCH*SEQ_LEN)   // 8192
#define NCHUNK  32
#define CHUNK_L (SEQ_LEN/NCHUNK)   // 64
#define LN_EPS  1e-5f

typedef __hip_bfloat16 bf16;
typedef __attribute__((ext_vector_type(8))) short bf16x8;
typedef __attribute__((ext_vector_type(4))) float f32x4;

// async global->LDS, 16B per lane; LDS dest is wave-uniform base + lane*16
__device__ __forceinline__ void gload16(const bf16* g, bf16* l) {
    __builtin_amdgcn_global_load_lds(
        (const __attribute__((address_space(1))) void*)g,
        (__attribute__((address_space(3))) void*)l, 16, 0, 0);
}

// ---------------- cast f32 -> bf16, vectorized ----------------
__global__ void cast4(const float4* __restrict__ in, ushort4* __restrict__ out, int n4) {
    int i = blockIdx.x * blockDim.x + threadIdx.x;
    if (i < n4) {
        float4 v = in[i];
        union { ushort4 u; bf16 b[4]; } cv;
        cv.b[0] = __float2bfloat16(v.x); cv.b[1] = __float2bfloat16(v.y);
        cv.b[2] = __float2bfloat16(v.z); cv.b[3] = __float2bfloat16(v.w);
        out[i] = cv.u;
    }
}

// ---------------- p, p^64 from phazor ----------------
__global__ void compute_pvec(const float* __restrict__ phz, float* __restrict__ pv) {
    int d = blockIdx.x * blockDim.x + threadIdx.x;
    if (d >= D_MODEL) return;
    float re = phz[2*d], im = phz[2*d+1];
    float r2 = re*re + im*im;
    float mag = expf(-r2);
    float pr, pim;
    if (r2 > 0.f) { float inv = mag / sqrtf(r2); pr = re*inv; pim = im*inv; }
    else          { pr = mag; pim = 0.f; }
    float ar = pr, ai = pim;
    #pragma unroll
    for (int i = 0; i < 6; i++) { float nr = ar*ar - ai*ai; float ni = 2.f*ar*ai; ar = nr; ai = ni; }
    pv[d]            = pr;
    pv[D_MODEL+d]    = pim;
    pv[2*D_MODEL+d]  = ar;
    pv[3*D_MODEL+d]  = ai;
}

// ---------------- LayerNorm (+ optional raw-x bf16 cast output) ----------------
__global__ __launch_bounds__(256) void ln_fused(const float* __restrict__ x,
                                                const float* __restrict__ g,
                                                const float* __restrict__ bta,
                                                float* __restrict__ outf,
                                                bf16*  __restrict__ outb,
                                                bf16*  __restrict__ rawb)
{
    int row = blockIdx.x;
    int tid = threadIdx.x;
    const float4* xr = (const float4*)(x + (size_t)row * D_MODEL);
    float4 v = xr[tid];
    if (rawb) {
        union { ushort4 u; bf16 b[4]; } cv;
        cv.b[0]=__float2bfloat16(v.x); cv.b[1]=__float2bfloat16(v.y);
        cv.b[2]=__float2bfloat16(v.z); cv.b[3]=__float2bfloat16(v.w);
        ((ushort4*)(rawb + (size_t)row * D_MODEL))[tid] = cv.u;
    }
    float s  = v.x + v.y + v.z + v.w;
    float s2 = v.x*v.x + v.y*v.y + v.z*v.z + v.w*v.w;
    for (int off = 32; off; off >>= 1) { s += __shfl_down(s, off); s2 += __shfl_down(s2, off); }
    __shared__ float red[8];
    int wid = tid >> 6, lane = tid & 63;
    if (lane == 0) { red[wid] = s; red[4+wid] = s2; }
    __syncthreads();
    if (tid == 0) {
        red[0] = red[0]+red[1]+red[2]+red[3];
        red[4] = red[4]+red[5]+red[6]+red[7];
    }
    __syncthreads();
    float mu  = red[0] * (1.f/D_MODEL);
    float var = red[4] * (1.f/D_MODEL) - mu*mu;
    float rstd = rsqrtf(var + LN_EPS);
    float4 gv = ((const float4*)g)[tid];
    float4 bv = ((const float4*)bta)[tid];
    float4 o;
    o.x = (v.x-mu)*rstd*gv.x + bv.x;
    o.y = (v.y-mu)*rstd*gv.y + bv.y;
    o.z = (v.z-mu)*rstd*gv.z + bv.z;
    o.w = (v.w-mu)*rstd*gv.w + bv.w;
    if (outf) ((float4*)(outf + (size_t)row * D_MODEL))[tid] = o;
    if (outb) {
        union { ushort4 u; bf16 b[4]; } cv;
        cv.b[0]=__float2bfloat16(o.x); cv.b[1]=__float2bfloat16(o.y);
        cv.b[2]=__float2bfloat16(o.z); cv.b[3]=__float2bfloat16(o.w);
        ((ushort4*)(outb + (size_t)row * D_MODEL))[tid] = cv.u;
    }
}

// ---------------- scan pass 1: per-chunk local state (zero init) ----------------
__global__ __launch_bounds__(256) void scan_pass1(const float* __restrict__ xn,
                                                  const float* __restrict__ pv,
                                                  const float* __restrict__ pini,
                                                  float* __restrict__ Sc)
{
    int d = blockIdx.x * 256 + threadIdx.x;
    int c = blockIdx.y, b = blockIdx.z;
    float pr = pv[d], pim = pv[D_MODEL+d];
    float icr = pini[2*d], ici = pini[2*d+1];
    float Sr = 0.f, Si = 0.f;
    const float* xp = xn + ((size_t)b*SEQ_LEN + c*CHUNK_L) * D_MODEL + d;
    #pragma unroll 8
    for (int i = 0; i < CHUNK_L; i++) {
        float xv = xp[(size_t)i * D_MODEL];
        float nr = pr*Sr - pim*Si + icr*xv;
        float ni = pr*Si + pim*Sr + ici*xv;
        Sr = nr; Si = ni;
    }
    size_t o = ((size_t)b*NCHUNK + c) * D_MODEL + d;
    Sc[2*o] = Sr; Sc[2*o+1] = Si;
}

// ---------------- scan pass 2: exclusive prefix over chunks (init = hidden) ----------------
__global__ __launch_bounds__(256) void scan_prefix(const float* __restrict__ Sc,
                                                   const float* __restrict__ pv,
                                                   const float* __restrict__ hr,
                                                   const float* __restrict__ hi,
                                                   float* __restrict__ pref)
{
    int d = blockIdx.x * 256 + threadIdx.x;
    int b = blockIdx.y;
    float qr = pv[2*D_MODEL+d], qi = pv[3*D_MODEL+d];   // p^64
    float Ur = hr[b*D_MODEL+d], Ui = hi[b*D_MODEL+d];
    for (int c = 0; c < NCHUNK; c++) {
        size_t o = ((size_t)b*NCHUNK + c) * D_MODEL + d;
        pref[2*o] = Ur; pref[2*o+1] = Ui;
        float sr = Sc[2*o], si = Sc[2*o+1];
        float nr = qr*Ur - qi*Ui + sr;
        float ni = qr*Ui + qi*Ur + si;
        Ur = nr; Ui = ni;
    }
}

// ---------------- scan pass 3: final states, write conv_with_past ----------------
__global__ __launch_bounds__(256) void scan_pass2(const float* __restrict__ xn,
                                                  const float* __restrict__ pv,
                                                  const float* __restrict__ pini,
                                                  const float* __restrict__ pref,
                                                  float* __restrict__ cwp,
                                                  int interleaved)
{
    int d = blockIdx.x * 256 + threadIdx.x;
    int c = blockIdx.y, b = blockIdx.z;
    float pr = pv[d], pim = pv[D_MODEL+d];
    float icr = pini[2*d], ici = pini[2*d+1];
    size_t po = ((size_t)b*NCHUNK + c) * D_MODEL + d;
    float Ur = pref[2*po], Ui = pref[2*po+1];
    size_t base = ((size_t)b*SEQ_LEN + c*CHUNK_L) * D_MODEL + d;
    const float* xp = xn + base;
    if (interleaved) {
        float2* cp = (float2*)cwp + base;
        #pragma unroll 8
        for (int i = 0; i < CHUNK_L; i++) {
            float xv = xp[(size_t)i * D_MODEL];
            float nr = pr*Ur - pim*Ui + icr*xv;
            float ni = pr*Ui + pim*Ur + ici*xv;
            Ur = nr; Ui = ni;
            cp[(size_t)i * D_MODEL] = make_float2(Ur, Ui);
        }
    } else {
        float* cp = cwp + base;
        #pragma unroll 8
        for (int i = 0; i < CHUNK_L; i++) {
            float xv = xp[(size_t)i * D_MODEL];
            float nr = pr*Ur - pim*Ui + icr*xv;
            float ni = pr*Ui + pim*Ur + ici*xv;
            Ur = nr; Ui = ni;
            cp[(size_t)i * D_MODEL] = Ur;
        }
    }
}

// ---------------- bf16 MFMA GEMM: depth-3 LDS pipeline, counted vmcnt ----------------
// LDS: 3 rotating slots of linear [128][32] bf16. Both-sides chunk swizzle
// (phys chunk = logical ^ ((row>>1)&3)) via pre-swizzled global source + same
// XOR on ds_read address (0 bank conflicts, verified round 4/5).
// Pipeline: prologue stages tiles 0..2; main iter t waits vmcnt(8) (own slot's
// loads landed; barrier joins all waves), ds_read+MFMA, barrier, stage tile t+3.
// Tail: 3 peeled iterations drain vmcnt 8 -> 4 -> 0 (no wasted wrap-staging,
// which cost ~98 MB/dispatch in round 5).
// Plain blockIdx tile mapping: default round-robin XCD placement keeps per-XCD
// A-footprint at A/8 (L2-resident); the round-5 swizzle inverted this (287 MB).
// EPI 0: x2 = cwp_real * silu(acc + bias) + x_res   (writes f32)
// EPI 1: h  = silu(acc + bias)                      (writes bf16)
// EPI 2: out = acc + bias + x2                      (writes f32)
#define BM 128
#define BN 128
#define BK 32

template<int EPI>
__global__ __launch_bounds__(256) void gemm_bt(const bf16* __restrict__ A,
                                               const bf16* __restrict__ Bt,
                                               const float* __restrict__ bias,
                                               const float* __restrict__ e0, int e0_stride,
                                               const float* __restrict__ e1,
                                               float* __restrict__ outf,
                                               bf16*  __restrict__ outb,
                                               int M, int N, int K)
{
    __shared__ __align__(16) bf16 As[3][BM*BK];
    __shared__ __align__(16) bf16 Bs[3][BM*BK];
    int tid = threadIdx.x;
    int m0 = blockIdx.x * BM;
    int n0 = blockIdx.y * BN;

    int wid = tid >> 6, lane = tid & 63;
    int wm = (wid >> 1) * 64, wn = (wid & 1) * 64;
    int lr = lane & 15;
    int lkc = lane >> 4;           // logical k-chunk 0..3

    // staging: wave w covers rows [w*16,w*16+16) and [64+w*16,...); lane l ->
    // (row = l>>2, phys chunk = l&3), fetch logical chunk (l&3)^((row>>1)&3).
    int rl = lane >> 2;
    int cS = (lane & 3) ^ ((rl >> 1) & 3);
    const bf16* gA0 = A  + (size_t)(m0 +      wid*16 + rl) * K + cS*8;
    const bf16* gA1 = A  + (size_t)(m0 + 64 + wid*16 + rl) * K + cS*8;
    const bf16* gB0 = Bt + (size_t)(n0 +      wid*16 + rl) * K + cS*8;
    const bf16* gB1 = Bt + (size_t)(n0 + 64 + wid*16 + rl) * K + cS*8;
    int lo0 = (     wid*16) * BK;
    int lo1 = (64 + wid*16) * BK;

    // fragment read offsets (elements within a slot), swizzled
    int keyr = (lr >> 1) & 3;
    int cR = (lkc ^ keyr) * 8;
    int offA[4], offB[4];
    #pragma unroll
    for (int i = 0; i < 4; i++) {
        offA[i] = (wm + i*16 + lr) * BK + cR;
        offB[i] = (wn + i*16 + lr) * BK + cR;
    }

    int nt = K / BK;   // 32 or 128
    auto stage = [&](int slot, int tile) {
        int k0 = tile * BK;
        gload16(gA0 + k0, &As[slot][lo0]);
        gload16(gA1 + k0, &As[slot][lo1]);
        gload16(gB0 + k0, &Bs[slot][lo0]);
        gload16(gB1 + k0, &Bs[slot][lo1]);
    };
    f32x4 acc[4][4] = {};
    auto compute = [&](int slot) {
        bf16x8 af[4], bfv[4];
        #pragma unroll
        for (int i = 0; i < 4; i++) {
            af[i]  = *(const bf16x8*)&As[slot][offA[i]];
            bfv[i] = *(const bf16x8*)&Bs[slot][offB[i]];
        }
        #pragma unroll
        for (int i = 0; i < 4; i++)
            #pragma unroll
            for (int j = 0; j < 4; j++)
                acc[i][j] = __builtin_amdgcn_mfma_f32_16x16x32_bf16(af[i], bfv[j], acc[i][j], 0, 0, 0);
    };

    stage(0, 0); stage(1, 1); stage(2, 2);   // 12 loads in flight per wave

    int s = 0;
    for (int t = 0; t < nt - 3; ++t) {
        // own slot-s loads done when <=8 of this wave's 12 remain outstanding
        asm volatile("s_waitcnt vmcnt(8)" ::: "memory");
        __builtin_amdgcn_s_barrier();            // all waves' slot-s loads landed
        __builtin_amdgcn_sched_barrier(0);
        compute(s);
        asm volatile("" ::: "memory");           // pin ds_reads above the barrier
        __builtin_amdgcn_s_barrier();            // all waves done reading slot s
        stage(s, t + 3);
        s = (s == 2) ? 0 : s + 1;
    }
    // tail: drain 3 remaining tiles, no further staging
    asm volatile("s_waitcnt vmcnt(8)" ::: "memory");
    __builtin_amdgcn_s_barrier();
    __builtin_amdgcn_sched_barrier(0);
    compute(s);
    s = (s == 2) ? 0 : s + 1;
    asm volatile("s_waitcnt vmcnt(4)" ::: "memory");
    __builtin_amdgcn_s_barrier();
    __builtin_amdgcn_sched_barrier(0);
    compute(s);
    s = (s == 2) ? 0 : s + 1;
    asm volatile("s_waitcnt vmcnt(0)" ::: "memory");
    __builtin_amdgcn_s_barrier();
    __builtin_amdgcn_sched_barrier(0);
    compute(s);

    int mrow = 4 * (lane >> 4);
    #pragma unroll
    for (int i = 0; i < 4; i++) {
        #pragma unroll
        for (int j = 0; j < 4; j++) {
            int nb = n0 + wn + j*16 + lr;
            float bb = bias[nb];
            #pragma unroll
            for (int r = 0; r < 4; r++) {
                int m = m0 + wm + i*16 + mrow + r;
                size_t idx = (size_t)m * N + nb;
                float v = acc[i][j][r] + bb;
                if (EPI == 0) {
                    float yv = v / (1.f + __expf(-v));
                    float sxv = e0[idx * (size_t)e0_stride];   // cwp real part
                    outf[idx] = sxv * yv + e1[idx];
                } else if (EPI == 1) {
                    float yv = v / (1.f + __expf(-v));
                    outb[idx] = __float2bfloat16(yv);
                } else {
                    outf[idx] = v + e0[idx];
                }
            }
        }
    }
}

extern "C" void kernel_launch(void* const* d_in, const int* in_sizes, int n_in,
                              void* d_out, int out_size, void* d_ws, size_t ws_size,
                              hipStream_t stream)
{
    const float* x    = (const float*)d_in[0];
    const float* hr   = (const float*)d_in[1];
    const float* hi   = (const float*)d_in[2];
    const float* pini = (const float*)d_in[3];
    const float* phz  = (const float*)d_in[4];
    const float* fcw  = (const float*)d_in[5];
    const float* fcb  = (const float*)d_in[6];
    const float* w1   = (const float*)d_in[7];
    const float* b1   = (const float*)d_in[8];
    const float* w2   = (const float*)d_in[9];
    const float* b2   = (const float*)d_in[10];
    const float* lng  = (const float*)d_in[11];
    const float* lnb  = (const float*)d_in[12];

    float* out = (float*)d_out;
    float* cwp = out + (size_t)NROWS * D_MODEL;
    int interleaved = (out_size >= NROWS * D_MODEL * 3) ? 1 : 0;

    char* ws = (char*)d_ws;
    size_t off = 0;
    bf16*  wfcb = (bf16*)(ws + off);  off += (size_t)D_MODEL*D_MODEL*2;
    bf16*  w1b  = (bf16*)(ws + off);  off += (size_t)D_FF*D_MODEL*2;
    bf16*  w2b  = (bf16*)(ws + off);  off += (size_t)D_MODEL*D_FF*2;
    float* pv   = (float*)(ws + off); off += (size_t)4*D_MODEL*4;
    float* xn   = (float*)(ws + off); off += (size_t)NROWS*D_MODEL*4;
    bf16*  xbf  = (bf16*)(ws + off);  off += (size_t)NROWS*D_MODEL*2;
    float* Sc   = (float*)(ws + off); off += (size_t)NBATCH*NCHUNK*D_MODEL*2*4;
    float* pref = (float*)(ws + off); off += (size_t)NBATCH*NCHUNK*D_MODEL*2*4;
    float* x2   = (float*)(ws + off); off += (size_t)NROWS*D_MODEL*4;
    bf16*  x3b  = (bf16*)(ws + off);  off += (size_t)NROWS*D_MODEL*2;
    bf16*  hbuf = (bf16*)(ws + off);  off += (size_t)NROWS*D_FF*2;

    // weight casts to bf16 (x cast is fused into the first LayerNorm)
    cast4<<<1024, 256, 0, stream>>>((const float4*)fcw, (ushort4*)wfcb, D_MODEL*D_MODEL/4);
    cast4<<<4096, 256, 0, stream>>>((const float4*)w1,  (ushort4*)w1b,  D_FF*D_MODEL/4);
    cast4<<<4096, 256, 0, stream>>>((const float4*)w2,  (ushort4*)w2b,  D_MODEL*D_FF/4);

    compute_pvec<<<4, 256, 0, stream>>>(phz, pv);

    // xn = LN(x) in f32 (scan input); also xbf = bf16(x) for the gate GEMM
    ln_fused<<<NROWS, 256, 0, stream>>>(x, lng, lnb, xn, nullptr, xbf);

    // chunked linear scan: U[l] = p*U[l-1] + init_c*xn[l], U[-1]=hidden; cwp = U
    scan_pass1<<<dim3(4, NCHUNK, NBATCH), 256, 0, stream>>>(xn, pv, pini, Sc);
    scan_prefix<<<dim3(4, NBATCH), 256, 0, stream>>>(Sc, pv, hr, hi, pref);
    scan_pass2<<<dim3(4, NCHUNK, NBATCH), 256, 0, stream>>>(xn, pv, pini, pref, cwp, interleaved);

    // gate: x2 = real(cwp) * silu(x @ fc_w^T + fc_b) + x
    gemm_bt<0><<<dim3(NROWS/BM, D_MODEL/BN), 256, 0, stream>>>(
        xbf, wfcb, fcb, cwp, interleaved ? 2 : 1, x, x2, nullptr, NROWS, D_MODEL, D_MODEL);

    // x3 = LN(x2) -> bf16
    ln_fused<<<NROWS, 256, 0, stream>>>(x2, lng, lnb, nullptr, x3b, nullptr);

    // h = silu(x3 @ w1^T + b1) -> bf16
    gemm_bt<1><<<dim3(NROWS/BM, D_FF/BN), 256, 0, stream>>>(
        x3b, w1b, b1, nullptr, 1, nullptr, nullptr, hbuf, NROWS, D_FF, D_MODEL);

    // out = h @ w2^T + b2 + x2
    gemm_bt<2><<<dim3(NROWS/BM, D_MODEL/BN), 256, 0, stream>>>(
        hbuf, w2b, b2, x2, 1, nullptr, out, nullptr, NROWS, D_MODEL, D_FF);
}

// Round 8
// 271.820 us; speedup vs baseline: 1.2460x; 1.0106x over previous
//
#include <hip/hip_runtime.h>
#include <hip/hip_bf16.h>

#define D_MODEL 1024
#define D_FF    4096
#define SEQ_LEN 2048
#define NBATCH  4
#define NROWS   (NBATCH*SEQ_LEN)   // 8192
#define NCHUNK  32
#define CHUNK_L (SEQ_LEN/NCHUNK)   // 64
#define LN_EPS  1e-5f

typedef __hip_bfloat16 bf16;
typedef __attribute__((ext_vector_type(8))) short bf16x8;
typedef __attribute__((ext_vector_type(4))) float f32x4;

// async global->LDS, 16B per lane; LDS dest is wave-uniform base + lane*16
__device__ __forceinline__ void gload16(const bf16* g, bf16* l) {
    __builtin_amdgcn_global_load_lds(
        (const __attribute__((address_space(1))) void*)g,
        (__attribute__((address_space(3))) void*)l, 16, 0, 0);
}

// ---------------- cast f32 -> bf16, vectorized ----------------
__global__ void cast4(const float4* __restrict__ in, ushort4* __restrict__ out, int n4) {
    int i = blockIdx.x * blockDim.x + threadIdx.x;
    if (i < n4) {
        float4 v = in[i];
        union { ushort4 u; bf16 b[4]; } cv;
        cv.b[0] = __float2bfloat16(v.x); cv.b[1] = __float2bfloat16(v.y);
        cv.b[2] = __float2bfloat16(v.z); cv.b[3] = __float2bfloat16(v.w);
        out[i] = cv.u;
    }
}

// ---------------- p, p^64 from phazor ----------------
__global__ void compute_pvec(const float* __restrict__ phz, float* __restrict__ pv) {
    int d = blockIdx.x * blockDim.x + threadIdx.x;
    if (d >= D_MODEL) return;
    float re = phz[2*d], im = phz[2*d+1];
    float r2 = re*re + im*im;
    float mag = expf(-r2);
    float pr, pim;
    if (r2 > 0.f) { float inv = mag / sqrtf(r2); pr = re*inv; pim = im*inv; }
    else          { pr = mag; pim = 0.f; }
    float ar = pr, ai = pim;
    #pragma unroll
    for (int i = 0; i < 6; i++) { float nr = ar*ar - ai*ai; float ni = 2.f*ar*ai; ar = nr; ai = ni; }
    pv[d]            = pr;
    pv[D_MODEL+d]    = pim;
    pv[2*D_MODEL+d]  = ar;
    pv[3*D_MODEL+d]  = ai;
}

// ---------------- LayerNorm (+ optional raw-x bf16 cast output) ----------------
__global__ __launch_bounds__(256) void ln_fused(const float* __restrict__ x,
                                                const float* __restrict__ g,
                                                const float* __restrict__ bta,
                                                float* __restrict__ outf,
                                                bf16*  __restrict__ outb,
                                                bf16*  __restrict__ rawb)
{
    int row = blockIdx.x;
    int tid = threadIdx.x;
    const float4* xr = (const float4*)(x + (size_t)row * D_MODEL);
    float4 v = xr[tid];
    if (rawb) {
        union { ushort4 u; bf16 b[4]; } cv;
        cv.b[0]=__float2bfloat16(v.x); cv.b[1]=__float2bfloat16(v.y);
        cv.b[2]=__float2bfloat16(v.z); cv.b[3]=__float2bfloat16(v.w);
        ((ushort4*)(rawb + (size_t)row * D_MODEL))[tid] = cv.u;
    }
    float s  = v.x + v.y + v.z + v.w;
    float s2 = v.x*v.x + v.y*v.y + v.z*v.z + v.w*v.w;
    for (int off = 32; off; off >>= 1) { s += __shfl_down(s, off); s2 += __shfl_down(s2, off); }
    __shared__ float red[8];
    int wid = tid >> 6, lane = tid & 63;
    if (lane == 0) { red[wid] = s; red[4+wid] = s2; }
    __syncthreads();
    if (tid == 0) {
        red[0] = red[0]+red[1]+red[2]+red[3];
        red[4] = red[4]+red[5]+red[6]+red[7];
    }
    __syncthreads();
    float mu  = red[0] * (1.f/D_MODEL);
    float var = red[4] * (1.f/D_MODEL) - mu*mu;
    float rstd = rsqrtf(var + LN_EPS);
    float4 gv = ((const float4*)g)[tid];
    float4 bv = ((const float4*)bta)[tid];
    float4 o;
    o.x = (v.x-mu)*rstd*gv.x + bv.x;
    o.y = (v.y-mu)*rstd*gv.y + bv.y;
    o.z = (v.z-mu)*rstd*gv.z + bv.z;
    o.w = (v.w-mu)*rstd*gv.w + bv.w;
    if (outf) ((float4*)(outf + (size_t)row * D_MODEL))[tid] = o;
    if (outb) {
        union { ushort4 u; bf16 b[4]; } cv;
        cv.b[0]=__float2bfloat16(o.x); cv.b[1]=__float2bfloat16(o.y);
        cv.b[2]=__float2bfloat16(o.z); cv.b[3]=__float2bfloat16(o.w);
        ((ushort4*)(outb + (size_t)row * D_MODEL))[tid] = cv.u;
    }
}

// ---------------- scan pass 1: per-chunk local state (zero init) ----------------
__global__ __launch_bounds__(256) void scan_pass1(const float* __restrict__ xn,
                                                  const float* __restrict__ pv,
                                                  const float* __restrict__ pini,
                                                  float* __restrict__ Sc)
{
    int d = blockIdx.x * 256 + threadIdx.x;
    int c = blockIdx.y, b = blockIdx.z;
    float pr = pv[d], pim = pv[D_MODEL+d];
    float icr = pini[2*d], ici = pini[2*d+1];
    float Sr = 0.f, Si = 0.f;
    const float* xp = xn + ((size_t)b*SEQ_LEN + c*CHUNK_L) * D_MODEL + d;
    #pragma unroll 8
    for (int i = 0; i < CHUNK_L; i++) {
        float xv = xp[(size_t)i * D_MODEL];
        float nr = pr*Sr - pim*Si + icr*xv;
        float ni = pr*Si + pim*Sr + ici*xv;
        Sr = nr; Si = ni;
    }
    size_t o = ((size_t)b*NCHUNK + c) * D_MODEL + d;
    Sc[2*o] = Sr; Sc[2*o+1] = Si;
}

// ---------------- scan pass 2: exclusive prefix over chunks (init = hidden) ----------------
__global__ __launch_bounds__(256) void scan_prefix(const float* __restrict__ Sc,
                                                   const float* __restrict__ pv,
                                                   const float* __restrict__ hr,
                                                   const float* __restrict__ hi,
                                                   float* __restrict__ pref)
{
    int d = blockIdx.x * 256 + threadIdx.x;
    int b = blockIdx.y;
    float qr = pv[2*D_MODEL+d], qi = pv[3*D_MODEL+d];   // p^64
    float Ur = hr[b*D_MODEL+d], Ui = hi[b*D_MODEL+d];
    for (int c = 0; c < NCHUNK; c++) {
        size_t o = ((size_t)b*NCHUNK + c) * D_MODEL + d;
        pref[2*o] = Ur; pref[2*o+1] = Ui;
        float sr = Sc[2*o], si = Sc[2*o+1];
        float nr = qr*Ur - qi*Ui + sr;
        float ni = qr*Ui + qi*Ur + si;
        Ur = nr; Ui = ni;
    }
}

// ---------------- scan pass 3: final states, write conv_with_past ----------------
__global__ __launch_bounds__(256) void scan_pass2(const float* __restrict__ xn,
                                                  const float* __restrict__ pv,
                                                  const float* __restrict__ pini,
                                                  const float* __restrict__ pref,
                                                  float* __restrict__ cwp,
                                                  int interleaved)
{
    int d = blockIdx.x * 256 + threadIdx.x;
    int c = blockIdx.y, b = blockIdx.z;
    float pr = pv[d], pim = pv[D_MODEL+d];
    float icr = pini[2*d], ici = pini[2*d+1];
    size_t po = ((size_t)b*NCHUNK + c) * D_MODEL + d;
    float Ur = pref[2*po], Ui = pref[2*po+1];
    size_t base = ((size_t)b*SEQ_LEN + c*CHUNK_L) * D_MODEL + d;
    const float* xp = xn + base;
    if (interleaved) {
        float2* cp = (float2*)cwp + base;
        #pragma unroll 8
        for (int i = 0; i < CHUNK_L; i++) {
            float xv = xp[(size_t)i * D_MODEL];
            float nr = pr*Ur - pim*Ui + icr*xv;
            float ni = pr*Ui + pim*Ur + ici*xv;
            Ur = nr; Ui = ni;
            cp[(size_t)i * D_MODEL] = make_float2(Ur, Ui);
        }
    } else {
        float* cp = cwp + base;
        #pragma unroll 8
        for (int i = 0; i < CHUNK_L; i++) {
            float xv = xp[(size_t)i * D_MODEL];
            float nr = pr*Ur - pim*Ui + icr*xv;
            float ni = pr*Ui + pim*Ur + ici*xv;
            Ur = nr; Ui = ni;
            cp[(size_t)i * D_MODEL] = Ur;
        }
    }
}

// ---------------- shared epilogue ----------------
template<int EPI>
__device__ __forceinline__ void epi_store(float v, size_t idx,
                                          const float* e0, int e0_stride, const float* e1,
                                          float* outf, bf16* outb)
{
    if (EPI == 0) {
        float yv = v / (1.f + __expf(-v));
        float sxv = e0[idx * (size_t)e0_stride];
        outf[idx] = sxv * yv + e1[idx];
    } else if (EPI == 1) {
        float yv = v / (1.f + __expf(-v));
        outb[idx] = __float2bfloat16(yv);
    } else {
        outf[idx] = v + e0[idx];
    }
}

// ---------------- bf16 MFMA GEMM 128x128: depth-3 LDS pipeline (proven r6) ----------------
#define BM 128
#define BN 128
#define BK 32

template<int EPI>
__global__ __launch_bounds__(256) void gemm_bt(const bf16* __restrict__ A,
                                               const bf16* __restrict__ Bt,
                                               const float* __restrict__ bias,
                                               const float* __restrict__ e0, int e0_stride,
                                               const float* __restrict__ e1,
                                               float* __restrict__ outf,
                                               bf16*  __restrict__ outb,
                                               int M, int N, int K)
{
    __shared__ __align__(16) bf16 As[3][BM*BK];
    __shared__ __align__(16) bf16 Bs[3][BM*BK];
    int tid = threadIdx.x;
    int m0 = blockIdx.x * BM;
    int n0 = blockIdx.y * BN;

    int wid = tid >> 6, lane = tid & 63;
    int wm = (wid >> 1) * 64, wn = (wid & 1) * 64;
    int lr = lane & 15;
    int lkc = lane >> 4;

    int rl = lane >> 2;
    int cS = (lane & 3) ^ ((rl >> 1) & 3);
    const bf16* gA0 = A  + (size_t)(m0 +      wid*16 + rl) * K + cS*8;
    const bf16* gA1 = A  + (size_t)(m0 + 64 + wid*16 + rl) * K + cS*8;
    const bf16* gB0 = Bt + (size_t)(n0 +      wid*16 + rl) * K + cS*8;
    const bf16* gB1 = Bt + (size_t)(n0 + 64 + wid*16 + rl) * K + cS*8;
    int lo0 = (     wid*16) * BK;
    int lo1 = (64 + wid*16) * BK;

    int keyr = (lr >> 1) & 3;
    int cR = (lkc ^ keyr) * 8;
    int offA[4], offB[4];
    #pragma unroll
    for (int i = 0; i < 4; i++) {
        offA[i] = (wm + i*16 + lr) * BK + cR;
        offB[i] = (wn + i*16 + lr) * BK + cR;
    }

    int nt = K / BK;
    auto stage = [&](int slot, int tile) {
        int k0 = tile * BK;
        gload16(gA0 + k0, &As[slot][lo0]);
        gload16(gA1 + k0, &As[slot][lo1]);
        gload16(gB0 + k0, &Bs[slot][lo0]);
        gload16(gB1 + k0, &Bs[slot][lo1]);
    };
    f32x4 acc[4][4] = {};
    auto compute = [&](int slot) {
        bf16x8 af[4], bfv[4];
        #pragma unroll
        for (int i = 0; i < 4; i++) {
            af[i]  = *(const bf16x8*)&As[slot][offA[i]];
            bfv[i] = *(const bf16x8*)&Bs[slot][offB[i]];
        }
        #pragma unroll
        for (int i = 0; i < 4; i++)
            #pragma unroll
            for (int j = 0; j < 4; j++)
                acc[i][j] = __builtin_amdgcn_mfma_f32_16x16x32_bf16(af[i], bfv[j], acc[i][j], 0, 0, 0);
    };

    stage(0, 0); stage(1, 1); stage(2, 2);

    int s = 0;
    for (int t = 0; t < nt - 3; ++t) {
        asm volatile("s_waitcnt vmcnt(8)" ::: "memory");
        __builtin_amdgcn_s_barrier();
        __builtin_amdgcn_sched_barrier(0);
        compute(s);
        asm volatile("" ::: "memory");
        __builtin_amdgcn_s_barrier();
        stage(s, t + 3);
        s = (s == 2) ? 0 : s + 1;
    }
    asm volatile("s_waitcnt vmcnt(8)" ::: "memory");
    __builtin_amdgcn_s_barrier();
    __builtin_amdgcn_sched_barrier(0);
    compute(s);
    s = (s == 2) ? 0 : s + 1;
    asm volatile("s_waitcnt vmcnt(4)" ::: "memory");
    __builtin_amdgcn_s_barrier();
    __builtin_amdgcn_sched_barrier(0);
    compute(s);
    s = (s == 2) ? 0 : s + 1;
    asm volatile("s_waitcnt vmcnt(0)" ::: "memory");
    __builtin_amdgcn_s_barrier();
    __builtin_amdgcn_sched_barrier(0);
    compute(s);

    int mrow = 4 * (lane >> 4);
    #pragma unroll
    for (int i = 0; i < 4; i++) {
        #pragma unroll
        for (int j = 0; j < 4; j++) {
            int nb = n0 + wn + j*16 + lr;
            float bb = bias[nb];
            #pragma unroll
            for (int r = 0; r < 4; r++) {
                int m = m0 + wm + i*16 + mrow + r;
                size_t idx = (size_t)m * N + nb;
                epi_store<EPI>(acc[i][j][r] + bb, idx, e0, e0_stride, e1, outf, outb);
            }
        }
    }
}

// ---------------- bf16 MFMA GEMM 256x256: same depth-3 pipeline, 8 waves ----------------
// Wave grid 2Mx4N; wave tile 128x64; 32 MFMA + 12 ds_read_b128 per K-tile per wave.
// Per-iter per-CU LDS traffic: 32KB staged + 96KB read vs 320 MFMA SIMD-cyc
// (2.1x better compute:LDS ratio than 128^2 -> attacks the round-6 LDS-BW bound).
// Staging/vmcnt accounting identical to gemm_bt: 4 gload16 per stage, 12 in
// flight, vmcnt 8/4/0. Same chunk-XOR swizzle (key=(row>>1)&3; wm,mf*16 are
// multiples of 4 so key reduces to (lr>>1)&3 -> identical 2-way-free math).
#define TM 256
#define TN 256

template<int EPI>
__global__ __launch_bounds__(512, 2) void gemm256(const bf16* __restrict__ A,
                                                  const bf16* __restrict__ Bt,
                                                  const float* __restrict__ bias,
                                                  const float* __restrict__ e0, int e0_stride,
                                                  const float* __restrict__ e1,
                                                  float* __restrict__ outf,
                                                  bf16*  __restrict__ outb,
                                                  int M, int N, int K)
{
    __shared__ __align__(16) bf16 As[3][TM*BK];
    __shared__ __align__(16) bf16 Bs[3][TN*BK];
    int tid = threadIdx.x;
    int m0 = blockIdx.x * TM;
    int n0 = blockIdx.y * TN;

    int wid = tid >> 6, lane = tid & 63;
    int wr = wid >> 2, wc = wid & 3;       // 2 x 4 wave grid
    int wm = wr * 128, wn = wc * 64;
    int lr = lane & 15;
    int lkc = lane >> 4;

    // staging: thread t covers rows (t>>2) and 128+(t>>2), phys chunk t&3.
    // key(row)=(row>>1)&3; key(row+128)==key(row).
    int rl = tid >> 2;                     // 0..127
    int cS = (tid & 3) ^ ((rl >> 1) & 3);
    const bf16* gA0 = A  + (size_t)(m0 +       rl) * K + cS*8;
    const bf16* gA1 = A  + (size_t)(m0 + 128 + rl) * K + cS*8;
    const bf16* gB0 = Bt + (size_t)(n0 +       rl) * K + cS*8;
    const bf16* gB1 = Bt + (size_t)(n0 + 128 + rl) * K + cS*8;
    int lo0 = (      wid*16) * BK;         // wave-uniform LDS bases (HW adds lane*16)
    int lo1 = (128 + wid*16) * BK;

    int keyr = (lr >> 1) & 3;
    int cR = (lkc ^ keyr) * 8;
    int offA[8], offB[4];
    #pragma unroll
    for (int i = 0; i < 8; i++) offA[i] = (wm + i*16 + lr) * BK + cR;
    #pragma unroll
    for (int j = 0; j < 4; j++) offB[j] = (wn + j*16 + lr) * BK + cR;

    int nt = K / BK;
    auto stage = [&](int slot, int tile) {
        int k0 = tile * BK;
        gload16(gA0 + k0, &As[slot][lo0]);
        gload16(gA1 + k0, &As[slot][lo1]);
        gload16(gB0 + k0, &Bs[slot][lo0]);
        gload16(gB1 + k0, &Bs[slot][lo1]);
    };
    f32x4 acc[8][4] = {};
    auto compute = [&](int slot) {
        bf16x8 af[8], bfv[4];
        #pragma unroll
        for (int i = 0; i < 8; i++) af[i]  = *(const bf16x8*)&As[slot][offA[i]];
        #pragma unroll
        for (int j = 0; j < 4; j++) bfv[j] = *(const bf16x8*)&Bs[slot][offB[j]];
        #pragma unroll
        for (int i = 0; i < 8; i++)
            #pragma unroll
            for (int j = 0; j < 4; j++)
                acc[i][j] = __builtin_amdgcn_mfma_f32_16x16x32_bf16(af[i], bfv[j], acc[i][j], 0, 0, 0);
    };

    stage(0, 0); stage(1, 1); stage(2, 2);   // 12 loads in flight per wave

    int s = 0;
    for (int t = 0; t < nt - 3; ++t) {
        asm volatile("s_waitcnt vmcnt(8)" ::: "memory");
        __builtin_amdgcn_s_barrier();
        __builtin_amdgcn_sched_barrier(0);
        compute(s);
        asm volatile("" ::: "memory");
        __builtin_amdgcn_s_barrier();
        stage(s, t + 3);
        s = (s == 2) ? 0 : s + 1;
    }
    asm volatile("s_waitcnt vmcnt(8)" ::: "memory");
    __builtin_amdgcn_s_barrier();
    __builtin_amdgcn_sched_barrier(0);
    compute(s);
    s = (s == 2) ? 0 : s + 1;
    asm volatile("s_waitcnt vmcnt(4)" ::: "memory");
    __builtin_amdgcn_s_barrier();
    __builtin_amdgcn_sched_barrier(0);
    compute(s);
    s = (s == 2) ? 0 : s + 1;
    asm volatile("s_waitcnt vmcnt(0)" ::: "memory");
    __builtin_amdgcn_s_barrier();
    __builtin_amdgcn_sched_barrier(0);
    compute(s);

    int mrow = 4 * (lane >> 4);
    #pragma unroll
    for (int i = 0; i < 8; i++) {
        #pragma unroll
        for (int j = 0; j < 4; j++) {
            int nb = n0 + wn + j*16 + lr;
            float bb = bias[nb];
            #pragma unroll
            for (int r = 0; r < 4; r++) {
                int m = m0 + wm + i*16 + mrow + r;
                size_t idx = (size_t)m * N + nb;
                epi_store<EPI>(acc[i][j][r] + bb, idx, e0, e0_stride, e1, outf, outb);
            }
        }
    }
}

extern "C" void kernel_launch(void* const* d_in, const int* in_sizes, int n_in,
                              void* d_out, int out_size, void* d_ws, size_t ws_size,
                              hipStream_t stream)
{
    const float* x    = (const float*)d_in[0];
    const float* hr   = (const float*)d_in[1];
    const float* hi   = (const float*)d_in[2];
    const float* pini = (const float*)d_in[3];
    const float* phz  = (const float*)d_in[4];
    const float* fcw  = (const float*)d_in[5];
    const float* fcb  = (const float*)d_in[6];
    const float* w1   = (const float*)d_in[7];
    const float* b1   = (const float*)d_in[8];
    const float* w2   = (const float*)d_in[9];
    const float* b2   = (const float*)d_in[10];
    const float* lng  = (const float*)d_in[11];
    const float* lnb  = (const float*)d_in[12];

    float* out = (float*)d_out;
    float* cwp = out + (size_t)NROWS * D_MODEL;
    int interleaved = (out_size >= NROWS * D_MODEL * 3) ? 1 : 0;

    char* ws = (char*)d_ws;
    size_t off = 0;
    bf16*  wfcb = (bf16*)(ws + off);  off += (size_t)D_MODEL*D_MODEL*2;
    bf16*  w1b  = (bf16*)(ws + off);  off += (size_t)D_FF*D_MODEL*2;
    bf16*  w2b  = (bf16*)(ws + off);  off += (size_t)D_MODEL*D_FF*2;
    float* pv   = (float*)(ws + off); off += (size_t)4*D_MODEL*4;
    float* xn   = (float*)(ws + off); off += (size_t)NROWS*D_MODEL*4;
    bf16*  xbf  = (bf16*)(ws + off);  off += (size_t)NROWS*D_MODEL*2;
    float* Sc   = (float*)(ws + off); off += (size_t)NBATCH*NCHUNK*D_MODEL*2*4;
    float* pref = (float*)(ws + off); off += (size_t)NBATCH*NCHUNK*D_MODEL*2*4;
    float* x2   = (float*)(ws + off); off += (size_t)NROWS*D_MODEL*4;
    bf16*  x3b  = (bf16*)(ws + off);  off += (size_t)NROWS*D_MODEL*2;
    bf16*  hbuf = (bf16*)(ws + off);  off += (size_t)NROWS*D_FF*2;

    // weight casts to bf16 (x cast is fused into the first LayerNorm)
    cast4<<<1024, 256, 0, stream>>>((const float4*)fcw, (ushort4*)wfcb, D_MODEL*D_MODEL/4);
    cast4<<<4096, 256, 0, stream>>>((const float4*)w1,  (ushort4*)w1b,  D_FF*D_MODEL/4);
    cast4<<<4096, 256, 0, stream>>>((const float4*)w2,  (ushort4*)w2b,  D_MODEL*D_FF/4);

    compute_pvec<<<4, 256, 0, stream>>>(phz, pv);

    // xn = LN(x) in f32 (scan input); also xbf = bf16(x) for the gate GEMM
    ln_fused<<<NROWS, 256, 0, stream>>>(x, lng, lnb, xn, nullptr, xbf);

    // chunked linear scan: U[l] = p*U[l-1] + init_c*xn[l], U[-1]=hidden; cwp = U
    scan_pass1<<<dim3(4, NCHUNK, NBATCH), 256, 0, stream>>>(xn, pv, pini, Sc);
    scan_prefix<<<dim3(4, NBATCH), 256, 0, stream>>>(Sc, pv, hr, hi, pref);
    scan_pass2<<<dim3(4, NCHUNK, NBATCH), 256, 0, stream>>>(xn, pv, pini, pref, cwp, interleaved);

    // gate: x2 = real(cwp) * silu(x @ fc_w^T + fc_b) + x
    gemm_bt<0><<<dim3(NROWS/BM, D_MODEL/BN), 256, 0, stream>>>(
        xbf, wfcb, fcb, cwp, interleaved ? 2 : 1, x, x2, nullptr, NROWS, D_MODEL, D_MODEL);

    // x3 = LN(x2) -> bf16
    ln_fused<<<NROWS, 256, 0, stream>>>(x2, lng, lnb, nullptr, x3b, nullptr);

    // h = silu(x3 @ w1^T + b1) -> bf16   (256^2 tile: full 512-block grid)
    gemm256<1><<<dim3(NROWS/TM, D_FF/TN), 512, 0, stream>>>(
        x3b, w1b, b1, nullptr, 1, nullptr, nullptr, hbuf, NROWS, D_FF, D_MODEL);

    // out = h @ w2^T + b2 + x2
    gemm_bt<2><<<dim3(NROWS/BM, D_MODEL/BN), 256, 0, stream>>>(
        hbuf, w2b, b2, x2, 1, nullptr, out, nullptr, NROWS, D_MODEL, D_FF);
}